// Round 1
// baseline (193.432 us; speedup 1.0000x reference)
//
#include <hip/hip_runtime.h>

// Fused attention: B=8, S=2048, D=512, fp32 in/out, bf16 MFMA compute.
// Pipeline: cvt(fp32->bf16) -> qkv_gemm (z=0/1/2 -> Q,K,Vt) -> flash attn.
// Vt is stored [B][D][S] so PV B-fragments are contiguous ds_read_b128.

typedef unsigned short u16;
typedef unsigned int u32;
typedef u16 u16x4 __attribute__((ext_vector_type(4)));
typedef float f32x4 __attribute__((ext_vector_type(4)));
typedef __bf16 bf16x8 __attribute__((ext_vector_type(8)));

#define NBATCH 8
#define NS 2048
#define ND 512
#define NM (NBATCH*NS)  // 16384 tokens

typedef __attribute__((address_space(1))) u32 gu32;
typedef __attribute__((address_space(3))) u32 lu32;
// 16B-wide async global->LDS. LDS dest is wave-uniform base (+lane*16 by HW);
// global source is per-lane.
#define GLD16(g, l) __builtin_amdgcn_global_load_lds((gu32*)(g), (lu32*)(l), 16, 0, 0)

__device__ __forceinline__ u16 f2bf(float f) {  // RNE fp32->bf16
  union { float f; u32 u; } v; v.f = f;
  u32 r = v.u + 0x7FFFu + ((v.u >> 16) & 1u);
  return (u16)(r >> 16);
}

__device__ __forceinline__ f32x4 mfma16(bf16x8 a, bf16x8 b, f32x4 c) {
  return __builtin_amdgcn_mfma_f32_16x16x32_bf16(a, b, c, 0, 0, 0);
}

// ---------------- fp32 -> bf16 convert (batch + 3 weight matrices) ----------
__global__ void cvt_kernel(const float* __restrict__ batch,
                           const float* __restrict__ wq,
                           const float* __restrict__ wk,
                           const float* __restrict__ wv,
                           u16* __restrict__ Xb, u16* __restrict__ Wqb,
                           u16* __restrict__ Wkb, u16* __restrict__ Wvb) {
  const int MD4 = NM * ND / 4;   // 2097152 float4s
  const int W4 = ND * ND / 4;    // 65536 float4s
  int total = MD4 + 3 * W4;
  for (int i = blockIdx.x * blockDim.x + threadIdx.x; i < total;
       i += gridDim.x * blockDim.x) {
    const float4* src; u16x4* dst; int off;
    if (i < MD4)             { src = (const float4*)batch; dst = (u16x4*)Xb;  off = i; }
    else if (i < MD4 + W4)   { src = (const float4*)wq;    dst = (u16x4*)Wqb; off = i - MD4; }
    else if (i < MD4 + 2*W4) { src = (const float4*)wk;    dst = (u16x4*)Wkb; off = i - MD4 - W4; }
    else                     { src = (const float4*)wv;    dst = (u16x4*)Wvb; off = i - MD4 - 2*W4; }
    float4 v = src[off];
    u16x4 o; o[0] = f2bf(v.x); o[1] = f2bf(v.y); o[2] = f2bf(v.z); o[3] = f2bf(v.w);
    dst[off] = o;
  }
}

// ---------------- QKV projection GEMM: C[m][n] = X[m][:] . W[n][:] + b ------
// 128x128 tile, BK=64, 4 waves (2x2), 16x16x32 MFMA, global_load_lds staging.
// z=0: Q (bias then *1/sqrt(D)), z=1: K, z=2: V written transposed to Vt[B][D][S].
__global__ __launch_bounds__(256) void qkv_gemm(
    const u16* __restrict__ Xb,
    const u16* __restrict__ Wqb, const u16* __restrict__ Wkb, const u16* __restrict__ Wvb,
    const float* __restrict__ bq, const float* __restrict__ bk, const float* __restrict__ bv,
    u16* __restrict__ Qb, u16* __restrict__ Kb, u16* __restrict__ Vt) {
  __shared__ u16 Asm[128 * 64];
  __shared__ u16 Bsm[128 * 64];
  int tid = threadIdx.x;
  int w = tid >> 6, lane = tid & 63, la = lane & 15, hi = lane >> 4;
  int wm = w >> 1, wn = w & 1;
  int m0 = blockIdx.x * 128, n0 = blockIdx.y * 128, z = blockIdx.z;
  const u16* W = (z == 0) ? Wqb : (z == 1) ? Wkb : Wvb;
  f32x4 acc[4][4];
  f32x4 zero = {0.f, 0.f, 0.f, 0.f};
#pragma unroll
  for (int mi = 0; mi < 4; ++mi)
#pragma unroll
    for (int ni = 0; ni < 4; ++ni) acc[mi][ni] = zero;

  for (int kt = 0; kt < 8; ++kt) {
#pragma unroll
    for (int i = 0; i < 4; ++i) {  // each wave stages 4 chunks of 1KB for A and B
      int c = w * 4 + i;
      int row = c * 8 + (lane >> 3);
      const char* ga = (const char*)Xb + ((size_t)(m0 + row) * ND + kt * 64) * 2 + (lane & 7) * 16;
      GLD16(ga, (char*)Asm + c * 1024);
      const char* gb = (const char*)W + ((size_t)(n0 + row) * ND + kt * 64) * 2 + (lane & 7) * 16;
      GLD16(gb, (char*)Bsm + c * 1024);
    }
    __syncthreads();
#pragma unroll
    for (int kk = 0; kk < 2; ++kk) {
      bf16x8 a[4], bfr[4];
#pragma unroll
      for (int mi = 0; mi < 4; ++mi)
        a[mi] = *(const bf16x8*)((const char*)Asm + (wm * 64 + mi * 16 + la) * 128 + kk * 64 + hi * 16);
#pragma unroll
      for (int ni = 0; ni < 4; ++ni)
        bfr[ni] = *(const bf16x8*)((const char*)Bsm + (wn * 64 + ni * 16 + la) * 128 + kk * 64 + hi * 16);
#pragma unroll
      for (int mi = 0; mi < 4; ++mi)
#pragma unroll
        for (int ni = 0; ni < 4; ++ni)
          acc[mi][ni] = mfma16(a[mi], bfr[ni], acc[mi][ni]);
    }
    __syncthreads();
  }

  const float* bias = (z == 0) ? bq : (z == 1) ? bk : bv;
  float scl = (z == 0) ? 0.044194173824159216f : 1.0f;  // 1/sqrt(512) folded into Q
#pragma unroll
  for (int mi = 0; mi < 4; ++mi) {
#pragma unroll
    for (int ni = 0; ni < 4; ++ni) {
      int col = n0 + wn * 64 + ni * 16 + la;          // output feature
      int rbase = m0 + wm * 64 + mi * 16 + hi * 4;    // token row (4 consecutive in regs)
      float bc = bias[col];
      if (z == 2) {
        int bbx = rbase >> 11, s0 = rbase & 2047;     // 128-row tile never crosses batch
        u16x4 pk;
#pragma unroll
        for (int j = 0; j < 4; ++j) pk[j] = f2bf(acc[mi][ni][j] + bc);
        *(u16x4*)((char*)Vt + (((size_t)bbx * ND + col) * NS + s0) * 2) = pk;
      } else {
        u16* Ob = (z == 0) ? Qb : Kb;
#pragma unroll
        for (int j = 0; j < 4; ++j)
          Ob[(size_t)(rbase + j) * ND + col] = f2bf((acc[mi][ni][j] + bc) * scl);
      }
    }
  }
}

// ---------------- flash attention -------------------------------------------
// Block = 4 waves, 64 q-rows (wave w owns rows q0+w*16..+16). K-tile BN=64.
// Swapped QK^T: S^T = mfma(Kfrag, Qfrag) so lane l&15 owns one q-row's scores.
// K LDS [64][512] and Vt LDS [512][64] staged with XOR swizzle byte^=(row&7)<<4
// applied on the per-lane GLOBAL source (LDS stays linear for global_load_lds).
__global__ __launch_bounds__(256, 1) void attn_kernel(
    const u16* __restrict__ Qb, const u16* __restrict__ Kb, const u16* __restrict__ Vt,
    const int* __restrict__ lens, float* __restrict__ out) {
  __shared__ u16 Ksm[64 * 512];    // 64 KB
  __shared__ u16 Vsm[512 * 64];    // 64 KB (transposed V tile: [d][k])
  __shared__ u16 Psm[4][16 * 72];  // per-wave P tile, padded stride 72 elems (144B)
  int tid = threadIdx.x;
  int w = tid >> 6, lane = tid & 63, la = lane & 15, hi = lane >> 4;
  int b = blockIdx.y, q0 = blockIdx.x * 64;
  int len = lens[b];
  int r0 = q0 + w * 16;
  int qrow = r0 + la;  // the q-row this lane owns in S^T domain

  // Q fragments (held whole kernel): lane reads Q[r0+la][kc*32 + hi*8 .. +8]
  bf16x8 qf[16];
  const char* qbase = (const char*)Qb + (size_t)(b * NS + r0 + la) * ND * 2 + hi * 16;
#pragma unroll
  for (int kc = 0; kc < 16; ++kc) qf[kc] = *(const bf16x8*)(qbase + kc * 64);

  f32x4 o[32];
  f32x4 zero = {0.f, 0.f, 0.f, 0.f};
#pragma unroll
  for (int i = 0; i < 32; ++i) o[i] = zero;
  float mrow = -1e30f, lrow = 0.f;

  int kmaxc = min(q0 + 63, len - 1);  // len>=1 so kmaxc>=0
  int ntiles = (kmaxc >> 6) + 1;

  for (int t = 0; t < ntiles; ++t) {
    int k0 = t * 64;
    // stage K tile: 64 rows x 1KB, 16 rows per wave, swizzled global source
#pragma unroll
    for (int i = 0; i < 16; ++i) {
      int r = w * 16 + i;
      const char* g = (const char*)Kb + (size_t)(b * NS + k0 + r) * ND * 2 + ((lane ^ (r & 7)) * 16);
      GLD16(g, (char*)Ksm + r * 1024);
    }
    // stage Vt tile: 512 rows x 128B, chunks of 8 rows, 16 chunks per wave
#pragma unroll
    for (int i = 0; i < 16; ++i) {
      int c = w * 16 + i;
      int d = c * 8 + (lane >> 3);
      const char* g = (const char*)Vt + ((size_t)(b * ND + d) * NS + k0) * 2 + (((lane & 7) ^ (d & 7)) * 16);
      GLD16(g, (char*)Vsm + c * 1024);
    }
    __syncthreads();

    // QK^T (transposed): s[f] holds keys f*16+hi*4+j (rows), q-col = la
    f32x4 s[4];
#pragma unroll
    for (int f = 0; f < 4; ++f) s[f] = zero;
#pragma unroll
    for (int kc = 0; kc < 16; ++kc) {
#pragma unroll
      for (int f = 0; f < 4; ++f) {
        int row = f * 16 + la;
        const char* p = (const char*)Ksm + row * 1024 + ((kc * 64 + hi * 16) ^ ((row & 7) * 16));
        bf16x8 kf = *(const bf16x8*)p;
        s[f] = mfma16(kf, qf[kc], s[f]);
      }
    }

    // mask + online softmax (per q-row = per lane la, replicated across hi)
    float tmax = -1e30f;
#pragma unroll
    for (int f = 0; f < 4; ++f) {
#pragma unroll
      for (int j = 0; j < 4; ++j) {
        int kabs = k0 + f * 16 + hi * 4 + j;
        bool ok = (kabs <= qrow) && (kabs < len);
        float vv = ok ? s[f][j] : -1e30f;
        s[f][j] = vv;
        tmax = fmaxf(tmax, vv);
      }
    }
    tmax = fmaxf(tmax, __shfl_xor(tmax, 16));
    tmax = fmaxf(tmax, __shfl_xor(tmax, 32));
    float mnew = fmaxf(mrow, tmax);
    float alpha = __expf(mrow - mnew);  // first tile: exp(-1e30-m)=0
    float psum = 0.f;
#pragma unroll
    for (int f = 0; f < 4; ++f) {
#pragma unroll
      for (int j = 0; j < 4; ++j) {
        float p = __expf(s[f][j] - mnew);
        s[f][j] = p;
        psum += p;
      }
    }
    psum += __shfl_xor(psum, 16);
    psum += __shfl_xor(psum, 32);
    lrow = lrow * alpha + psum;
    mrow = mnew;

    // P -> LDS (bf16) to re-layout into PV A-fragments (wave-private region)
#pragma unroll
    for (int f = 0; f < 4; ++f) {
      u16x4 pk;
#pragma unroll
      for (int j = 0; j < 4; ++j) pk[j] = f2bf(s[f][j]);
      *(u16x4*)((char*)&Psm[w][0] + la * 144 + (f * 16 + hi * 4) * 2) = pk;
    }

    // redistribute alpha from S^T domain (per la) to O domain (per hi*4+j)
    float aj[4];
#pragma unroll
    for (int j = 0; j < 4; ++j) aj[j] = __shfl(alpha, hi * 4 + j);
#pragma unroll
    for (int nb = 0; nb < 32; ++nb) {
      o[nb][0] *= aj[0]; o[nb][1] *= aj[1]; o[nb][2] *= aj[2]; o[nb][3] *= aj[3];
    }

    // PV: O[q][d] += P[q][k] * V[k][d]; B-frag = contiguous read from Vt LDS
#pragma unroll
    for (int ks = 0; ks < 2; ++ks) {
      bf16x8 pf = *(const bf16x8*)((const char*)&Psm[w][0] + la * 144 + ks * 64 + hi * 16);
#pragma unroll
      for (int nb = 0; nb < 32; ++nb) {
        int d = nb * 16 + la;
        const char* vp = (const char*)Vsm + d * 128 + ((ks * 64 + hi * 16) ^ ((d & 7) * 16));
        bf16x8 vf = *(const bf16x8*)vp;
        o[nb] = mfma16(pf, vf, o[nb]);
      }
    }
    __syncthreads();  // protect K/V LDS before next tile's staging
  }

  // epilogue: divide by softmax denom (redistribute lrow to O domain), store fp32
  float linv[4];
#pragma unroll
  for (int j = 0; j < 4; ++j) linv[j] = 1.0f / __shfl(lrow, hi * 4 + j);
  float* ob = out + (size_t)(b * NS + r0 + hi * 4) * ND + la;
#pragma unroll
  for (int nb = 0; nb < 32; ++nb)
#pragma unroll
    for (int j = 0; j < 4; ++j)
      ob[(size_t)j * ND + nb * 16] = o[nb][j] * linv[j];
}

extern "C" void kernel_launch(void* const* d_in, const int* in_sizes, int n_in,
                              void* d_out, int out_size, void* d_ws, size_t ws_size,
                              hipStream_t stream) {
  const float* batch = (const float*)d_in[0];
  const float* wq = (const float*)d_in[1];
  const float* bq = (const float*)d_in[2];
  const float* wk = (const float*)d_in[3];
  const float* bk = (const float*)d_in[4];
  const float* wv = (const float*)d_in[5];
  const float* bv = (const float*)d_in[6];
  const int* lens = (const int*)d_in[7];

  char* ws = (char*)d_ws;
  // workspace layout (bytes): total 68,681,728
  u16* Xb  = (u16*)(ws + 0);         // batch bf16      16 MB
  u16* Wqb = (u16*)(ws + 16777216);  // wq bf16         512 KB
  u16* Wkb = (u16*)(ws + 17301504);  // wk bf16         512 KB
  u16* Wvb = (u16*)(ws + 17825792);  // wv bf16         512 KB
  u16* Qb  = (u16*)(ws + 18350080);  // Q bf16 (scaled) 16 MB
  u16* Kb  = (u16*)(ws + 35127296);  // K bf16          16 MB
  u16* Vt  = (u16*)(ws + 51904512);  // V^T bf16 [B][D][S] 16 MB

  cvt_kernel<<<dim3(2048), dim3(256), 0, stream>>>(batch, wq, wk, wv, Xb, Wqb, Wkb, Wvb);
  qkv_gemm<<<dim3(128, 4, 3), dim3(256), 0, stream>>>(Xb, Wqb, Wkb, Wvb, bq, bk, bv, Qb, Kb, Vt);
  attn_kernel<<<dim3(32, 8), dim3(256), 0, stream>>>(Qb, Kb, Vt, lens, (float*)d_out);
}